// Round 23
// baseline (83.512 us; speedup 1.0000x reference)
//
#include <hip/hip_runtime.h>
#include <cmath>

namespace {

typedef __attribute__((ext_vector_type(8))) short short8;
typedef __attribute__((ext_vector_type(4))) float f32x4;
typedef __attribute__((ext_vector_type(4))) unsigned u32x4;

constexpr float kScale = 0.08838834764831845f;     // 128^-0.5
constexpr float kScaleL2 = 0.12751744900764504f;   // kScale * log2(e)

__device__ __forceinline__ int voxel_row(int p, int pix) {
  int pd = p >> 6, ph = (p >> 3) & 7, pw = p & 7;
  int iz = pix >> 4, iy = (pix >> 2) & 3, ix = pix & 3;
  return (((pd * 4 + iz) * 32 + (ph * 4 + iy)) * 32 + (pw * 4 + ix));
}

__device__ __forceinline__ float dot4(float4 a, float4 b) {
  return a.x * b.x + a.y * b.y + a.z * b.z + a.w * b.w;
}

__device__ __forceinline__ short bf16c(float f) {
  unsigned u = __builtin_bit_cast(unsigned, f);
  u += 0x7fffu + ((u >> 16) & 1u);
  return (short)(u >> 16);
}

__device__ __forceinline__ unsigned bfpack(float lo, float hi) {
  return (unsigned)(unsigned short)bf16c(lo) |
         ((unsigned)(unsigned short)bf16c(hi) << 16);
}

// ---- pack weights into per-lane MFMA B-fragments ----
__global__ __launch_bounds__(64) void k_pack2(
    const float* __restrict__ wqkv, const float* __restrict__ wo,
    short* __restrict__ dstq, short* __restrict__ dsto) {
  const int lane = threadIdx.x;
  const float* w;
  short* dst;
  int fid, N;
  if (blockIdx.x < 96) {
    w = wqkv; dst = dstq; fid = blockIdx.x; N = 384;
  } else {
    w = wo; dst = dsto; fid = blockIdx.x - 96; N = 128;
  }
  const int ntile = fid >> 2, ks = fid & 3;
  const int k0 = ks * 32 + (lane >> 4) * 8, col = ntile * 16 + (lane & 15);
  short8 o;
#pragma unroll
  for (int i = 0; i < 8; ++i) o[i] = bf16c(w[(size_t)(k0 + i) * N + col]);
  *(short8*)(dst + ((size_t)fid * 64 + lane) * 8) = o;
}

// ---- QKV projection: 512 thr / 8 waves x 3 col-tiles (unchanged) ----
__global__ __launch_bounds__(512, 4) void k_qkv(
    const float* __restrict__ x, const short* __restrict__ wpk,
    const float* __restrict__ bias, const float* __restrict__ wfull,
    float* __restrict__ q, float* __restrict__ k, float* __restrict__ v,
    short* __restrict__ vt, short* __restrict__ kbh, short* __restrict__ qbh,
    float* __restrict__ qwin, float* __restrict__ kwin) {
  __shared__ short sX[64][136];
  __shared__ float xpart[8][16][8];
  __shared__ float xm[128];
  const int p = blockIdx.x, t = threadIdx.x;
  const int wave = t >> 6, lane = t & 63, l15 = lane & 15, lg = lane >> 4;

  float ps[8] = {0.f, 0.f, 0.f, 0.f, 0.f, 0.f, 0.f, 0.f};
#pragma unroll
  for (int r = 0; r < 2; ++r) {
    int unit = t + r * 512;
    int row = unit >> 4, u = unit & 15;
    const float* src = x + (size_t)voxel_row(p, row) * 128 + u * 8;
    float4 a = *(const float4*)src, b = *(const float4*)(src + 4);
    ps[0] += a.x; ps[1] += a.y; ps[2] += a.z; ps[3] += a.w;
    ps[4] += b.x; ps[5] += b.y; ps[6] += b.z; ps[7] += b.w;
    short8 o;
    o[0] = bf16c(a.x); o[1] = bf16c(a.y); o[2] = bf16c(a.z); o[3] = bf16c(a.w);
    o[4] = bf16c(b.x); o[5] = bf16c(b.y); o[6] = bf16c(b.z); o[7] = bf16c(b.w);
    *(short8*)(&sX[row][u * 8]) = o;
  }
#pragma unroll
  for (int i = 0; i < 8; ++i) {
    ps[i] += __shfl_xor(ps[i], 16);
    ps[i] += __shfl_xor(ps[i], 32);
  }
  if (lg == 0)
#pragma unroll
    for (int i = 0; i < 8; ++i) xpart[wave][l15][i] = ps[i];
  __syncthreads();
  if (t < 128) {
    float s = 0.f;
#pragma unroll
    for (int w8 = 0; w8 < 8; ++w8) s += xpart[w8][t >> 3][t & 7];
    xm[t] = s * (1.f / 64.f);
  }

  f32x4 acc[4][3];
#pragma unroll
  for (int mt = 0; mt < 4; ++mt)
#pragma unroll
    for (int nt = 0; nt < 3; ++nt) acc[mt][nt] = f32x4{0.f, 0.f, 0.f, 0.f};
#pragma unroll
  for (int ks = 0; ks < 4; ++ks) {
    short8 a[4];
#pragma unroll
    for (int mt = 0; mt < 4; ++mt)
      a[mt] = *(const short8*)(&sX[mt * 16 + l15][ks * 32 + lg * 8]);
#pragma unroll
    for (int nt = 0; nt < 3; ++nt) {
      int ntg = wave * 3 + nt;
      short8 b = *(const short8*)(wpk + ((size_t)(ntg * 4 + ks) * 64 + lane) * 8);
#pragma unroll
      for (int mt = 0; mt < 4; ++mt)
        acc[mt][nt] = __builtin_amdgcn_mfma_f32_16x16x32_bf16(a[mt], b, acc[mt][nt], 0, 0, 0);
    }
  }
#pragma unroll
  for (int nt = 0; nt < 3; ++nt) {
    int n = (wave * 3 + nt) * 16 + l15;
    float bv = bias[n];
    float* dst = n < 128 ? q : (n < 256 ? k : v);
    int col = n & 127;
#pragma unroll
    for (int mt = 0; mt < 4; ++mt) {
      float o0 = acc[mt][nt][0] + bv, o1 = acc[mt][nt][1] + bv;
      float o2 = acc[mt][nt][2] + bv, o3 = acc[mt][nt][3] + bv;
      int row0 = mt * 16 + lg * 4;
      dst[(size_t)(p * 64 + row0 + 0) * 128 + col] = o0;
      dst[(size_t)(p * 64 + row0 + 1) * 128 + col] = o1;
      dst[(size_t)(p * 64 + row0 + 2) * 128 + col] = o2;
      dst[(size_t)(p * 64 + row0 + 3) * 128 + col] = o3;
      if (n >= 256) {
        uint2 pk;
        pk.x = bfpack(o0, o1);
        pk.y = bfpack(o2, o3);
        *(uint2*)(vt + (size_t)p * 8192 + (size_t)(n - 256) * 64 + row0) = pk;
      } else if (n >= 128) {
        int hh = (n - 128) >> 4, d = (n - 128) & 15;
        short* kd = kbh + (((size_t)(p * 8 + hh)) * 64 + row0) * 16 + d;
        kd[0] = bf16c(o0);
        kd[16] = bf16c(o1);
        kd[32] = bf16c(o2);
        kd[48] = bf16c(o3);
      } else {  // Q bf16 head-major, pre-scaled into log2 domain
        int hh = n >> 4, d = n & 15;
        short* qd = qbh + (((size_t)(p * 8 + hh)) * 64 + row0) * 16 + d;
        qd[0] = bf16c(o0 * kScaleL2);
        qd[16] = bf16c(o1 * kScaleL2);
        qd[32] = bf16c(o2 * kScaleL2);
        qd[48] = bf16c(o3 * kScaleL2);
      }
    }
  }

  __syncthreads();
  if (t < 256) {
    float acc2 = bias[t];
    for (int kk = 0; kk < 128; ++kk)
      acc2 = fmaf(xm[kk], wfull[(size_t)kk * 384 + t], acc2);
    if (t < 128) qwin[p * 128 + t] = acc2;
    else kwin[p * 128 + (t - 128)] = acc2;
  }
}

// ---- FUSED routing + attention + out-projection, chunk-split ----
// 1024 thr / 16 waves: wave = (half = w>>3, head = w&7). Each wave runs the
// R20 inner loop over 2 of the 4 routed windows; states merged via LDS
// flash-combine. Out-projection split over all 16 waves.
__global__ __launch_bounds__(1024, 4) void k_attn(
    const short* __restrict__ qbh, const short* __restrict__ kbh,
    const short* __restrict__ vt, const float* __restrict__ qwin,
    const float* __restrict__ kwin, const short* __restrict__ wpk_o,
    const float* __restrict__ b_o, float* __restrict__ out) {
  // union: routing (lgits 2KB + qs 512B) | exchange (48KB) | sO (17.4KB)
  __shared__ __align__(16) char smem[49152];
  float* lgits = (float*)smem;                 // [512]
  float* qs = (float*)(smem + 2048);           // [128]
  float* ex = (float*)smem;                    // [8][4][64][6] f32
  short* sO = (short*)smem;                    // [64][136]
  __shared__ int widx[4];

  const int p = blockIdx.x, t = threadIdx.x;
  const int wave = t >> 6, lane = t & 63;
  const int l15 = lane & 15, lg = lane >> 4;
  const int h = wave & 7, half = wave >> 3;

  // Q B-frags issued early (both halves load same head's Q)
  const short* qw = qbh + ((size_t)(p * 8 + h)) * 1024;
  short8 qf[4];
#pragma unroll
  for (int nt = 0; nt < 4; ++nt) {
    if (lg < 2)
      qf[nt] = *(const short8*)(qw + (nt * 16 + l15) * 16 + lg * 8);
    else
      qf[nt] = short8{0, 0, 0, 0, 0, 0, 0, 0};
  }

  // ---- routing: logits (threads < 512) ----
  if (t < 32) *(float4*)(&qs[t * 4]) = *(const float4*)(qwin + p * 128 + t * 4);
  __syncthreads();
  if (t < 512) {
    const float* kr = kwin + (size_t)t * 128;
    float s = 0.f;
    for (int c = 0; c < 128; c += 4)
      s += dot4(*(const float4*)(qs + c), *(const float4*)(kr + c));
    lgits[t] = s;
  }
  __syncthreads();
  // top-4 by wave 0: register-resident, winner cleared locally (R16)
  if (wave == 0) {
    float vals[8];
#pragma unroll
    for (int i = 0; i < 8; ++i) vals[i] = lgits[lane * 8 + i];
    for (int sel = 0; sel < 4; ++sel) {
      float bv = -1e30f;
      int bi = 0;
#pragma unroll
      for (int i = 0; i < 8; ++i) {
        int idx = lane * 8 + i;
        if (vals[i] > bv) { bv = vals[i]; bi = idx; }
      }
#pragma unroll
      for (int off = 32; off > 0; off >>= 1) {
        float ov = __shfl_xor(bv, off);
        int oi = __shfl_xor(bi, off);
        if (ov > bv || (ov == bv && oi < bi)) { bv = ov; bi = oi; }
      }
      if (lane == 0) widx[sel] = bi;
      if ((bi >> 3) == lane) vals[bi & 7] = -1e30f;
    }
  }
  __syncthreads();

  const int src0 = ((lg & 1) << 5) | l15;
  const int src1 = src0 + 16;

  float m_r[4] = {-1e30f, -1e30f, -1e30f, -1e30f};
  float l_r[4] = {0.f, 0.f, 0.f, 0.f};
  f32x4 oacc[4];
#pragma unroll
  for (int i = 0; i < 4; ++i) oacc[i] = f32x4{0.f, 0.f, 0.f, 0.f};

  // ---- attention over THIS WAVE'S 2 chunks (R20-identical inner body) ----
#pragma unroll
  for (int cc = 0; cc < 2; ++cc) {
    const int wsel = widx[half * 2 + cc];
    const short* kw = kbh + ((size_t)(wsel * 8 + h)) * 1024;
    short8 af[4];
#pragma unroll
    for (int mt = 0; mt < 4; ++mt) {
      if (lg < 2)
        af[mt] = *(const short8*)(kw + (mt * 16 + l15) * 16 + lg * 8);
      else
        af[mt] = short8{0, 0, 0, 0, 0, 0, 0, 0};
    }
    const short* vw = vt + (size_t)wsel * 8192 + (size_t)(h * 16 + l15) * 64 + lg * 8;
    short8 av0 = *(const short8*)(vw);
    short8 av1 = *(const short8*)(vw + 32);

#pragma unroll
    for (int np = 0; np < 2; ++np) {
      f32x4 s[4][2];
#pragma unroll
      for (int mt = 0; mt < 4; ++mt)
#pragma unroll
        for (int j2 = 0; j2 < 2; ++j2)
          s[mt][j2] = __builtin_amdgcn_mfma_f32_16x16x32_bf16(
              af[mt], qf[np * 2 + j2], f32x4{0.f, 0.f, 0.f, 0.f}, 0, 0, 0);

#pragma unroll
      for (int j2 = 0; j2 < 2; ++j2) {
        const int nt = np * 2 + j2;
        float mx = -1e30f;
#pragma unroll
        for (int mt = 0; mt < 4; ++mt)
#pragma unroll
          for (int j = 0; j < 4; ++j) mx = fmaxf(mx, s[mt][j2][j]);
        mx = fmaxf(mx, __shfl_xor(mx, 16));
        mx = fmaxf(mx, __shfl_xor(mx, 32));
        if (!__all(mx <= m_r[nt] + 11.0f)) {
          float mnew = fmaxf(m_r[nt], mx);
          float sc = __builtin_amdgcn_exp2f(m_r[nt] - mnew);
          m_r[nt] = mnew;
          l_r[nt] *= sc;
          oacc[nt][0] *= sc; oacc[nt][1] *= sc;
          oacc[nt][2] *= sc; oacc[nt][3] *= sc;
        }
        float ls = 0.f;
#pragma unroll
        for (int mt = 0; mt < 4; ++mt)
#pragma unroll
          for (int j = 0; j < 4; ++j) {
            float e = __builtin_amdgcn_exp2f(s[mt][j2][j] - m_r[nt]);
            s[mt][j2][j] = e;
            ls += e;
          }
        ls += __shfl_xor(ls, 16);
        ls += __shfl_xor(ls, 32);
        l_r[nt] += ls;

        unsigned P2[4][2];
#pragma unroll
        for (int mt = 0; mt < 4; ++mt) {
          P2[mt][0] = bfpack(s[mt][j2][0], s[mt][j2][1]);
          P2[mt][1] = bfpack(s[mt][j2][2], s[mt][j2][3]);
        }
#pragma unroll
        for (int kt = 0; kt < 2; ++kt) {
          unsigned lo0 = (unsigned)__shfl((int)P2[2 * kt + 0][0], src0);
          unsigned hi0 = (unsigned)__shfl((int)P2[2 * kt + 1][0], src0);
          unsigned lo1 = (unsigned)__shfl((int)P2[2 * kt + 0][1], src0);
          unsigned hi1 = (unsigned)__shfl((int)P2[2 * kt + 1][1], src0);
          unsigned lo2 = (unsigned)__shfl((int)P2[2 * kt + 0][0], src1);
          unsigned hi2 = (unsigned)__shfl((int)P2[2 * kt + 1][0], src1);
          unsigned lo3 = (unsigned)__shfl((int)P2[2 * kt + 0][1], src1);
          unsigned hi3 = (unsigned)__shfl((int)P2[2 * kt + 1][1], src1);
          u32x4 bw;
          bw[0] = (lg < 2) ? lo0 : hi0;
          bw[1] = (lg < 2) ? lo1 : hi1;
          bw[2] = (lg < 2) ? lo2 : hi2;
          bw[3] = (lg < 2) ? lo3 : hi3;
          short8 bfr = __builtin_bit_cast(short8, bw);
          oacc[nt] = __builtin_amdgcn_mfma_f32_16x16x32_bf16(
              kt == 0 ? av0 : av1, bfr, oacc[nt], 0, 0, 0);
        }
      }
    }
  }

  // ---- flash-combine the two halves via LDS ----
  if (half == 1) {
#pragma unroll
    for (int nt = 0; nt < 4; ++nt) {
      float* exw = ex + (((size_t)(h * 4 + nt) * 64 + lane) * 6);
      exw[0] = m_r[nt];
      exw[1] = l_r[nt];
      exw[2] = oacc[nt][0]; exw[3] = oacc[nt][1];
      exw[4] = oacc[nt][2]; exw[5] = oacc[nt][3];
    }
  }
  __syncthreads();
  if (half == 0) {
#pragma unroll
    for (int nt = 0; nt < 4; ++nt) {
      const float* exr = ex + (((size_t)(h * 4 + nt) * 64 + lane) * 6);
      float m2 = exr[0], l2 = exr[1];
      float mnew = fmaxf(m_r[nt], m2);
      float sc1 = __builtin_amdgcn_exp2f(m_r[nt] - mnew);
      float sc2 = __builtin_amdgcn_exp2f(m2 - mnew);
      l_r[nt] = l_r[nt] * sc1 + l2 * sc2;
      oacc[nt][0] = oacc[nt][0] * sc1 + exr[2] * sc2;
      oacc[nt][1] = oacc[nt][1] * sc1 + exr[3] * sc2;
      oacc[nt][2] = oacc[nt][2] * sc1 + exr[4] * sc2;
      oacc[nt][3] = oacc[nt][3] * sc1 + exr[5] * sc2;
    }
  }
  __syncthreads();  // ex reads done before sO overwrites same bytes

  // ---- O -> LDS (bf16), written by half 0 only ----
  if (half == 0) {
#pragma unroll
    for (int nt = 0; nt < 4; ++nt) {
      float inv = 1.f / l_r[nt];
      uint2 pk;
      pk.x = bfpack(oacc[nt][0] * inv, oacc[nt][1] * inv);
      pk.y = bfpack(oacc[nt][2] * inv, oacc[nt][3] * inv);
      *(uint2*)(&sO[(size_t)(nt * 16 + l15) * 136 + h * 16 + lg * 4]) = pk;
    }
  }
  __syncthreads();

  // ---- out-projection split over 16 waves: ct = w>>1, mt pair = w&1 ----
  {
    const int ct = wave >> 1, mh = wave & 1;
    const int mt0 = mh * 2, mt1 = mh * 2 + 1;
    f32x4 pacc0 = f32x4{0.f, 0.f, 0.f, 0.f};
    f32x4 pacc1 = f32x4{0.f, 0.f, 0.f, 0.f};
#pragma unroll
    for (int ks = 0; ks < 4; ++ks) {
      short8 a0 = *(const short8*)(&sO[(size_t)(mt0 * 16 + l15) * 136 + ks * 32 + lg * 8]);
      short8 a1 = *(const short8*)(&sO[(size_t)(mt1 * 16 + l15) * 136 + ks * 32 + lg * 8]);
      short8 b = *(const short8*)(wpk_o + ((size_t)(ct * 4 + ks) * 64 + lane) * 8);
      pacc0 = __builtin_amdgcn_mfma_f32_16x16x32_bf16(a0, b, pacc0, 0, 0, 0);
      pacc1 = __builtin_amdgcn_mfma_f32_16x16x32_bf16(a1, b, pacc1, 0, 0, 0);
    }
    int n = ct * 16 + l15;
    float bv = b_o[n];
#pragma unroll
    for (int j = 0; j < 4; ++j) {
      out[(size_t)voxel_row(p, mt0 * 16 + lg * 4 + j) * 128 + n] = pacc0[j] + bv;
      out[(size_t)voxel_row(p, mt1 * 16 + lg * 4 + j) * 128 + n] = pacc1[j] + bv;
    }
  }
}

}  // namespace

extern "C" void kernel_launch(void* const* d_in, const int* in_sizes, int n_in,
                              void* d_out, int out_size, void* d_ws, size_t ws_size,
                              hipStream_t stream) {
  (void)in_sizes; (void)n_in; (void)out_size; (void)ws_size;
  const float* x = (const float*)d_in[0];
  const float* w_qkv = (const float*)d_in[1];
  const float* b_qkv = (const float*)d_in[2];
  const float* w_o = (const float*)d_in[3];
  const float* b_o = (const float*)d_in[4];

  float* out = (float*)d_out;
  float* q = out + 4194304;
  float* k = q + 4194304;
  float* v = k + 4194304;

  float* qwin = (float*)d_ws;                 // 512*128 f32
  float* kwin = qwin + 65536;                 // 512*128 f32
  short* wpk_qkv = (short*)(kwin + 65536);    // 96 KB
  short* wpk_o = wpk_qkv + 49152;             // 32 KB
  short* vt = wpk_o + 16384;                  // 8 MB
  short* kbh = vt + 4194304;                  // 8 MB
  short* qbh = kbh + 4194304;                 // 8 MB

  k_pack2<<<128, 64, 0, stream>>>(w_qkv, w_o, wpk_qkv, wpk_o);
  k_qkv<<<512, 512, 0, stream>>>(x, wpk_qkv, b_qkv, w_qkv, q, k, v, vt, kbh, qbh, qwin, kwin);
  k_attn<<<512, 1024, 0, stream>>>(qbh, kbh, vt, qwin, kwin, wpk_o, b_o, out);
}

// Round 24
// 74.375 us; speedup vs baseline: 1.1228x; 1.1228x over previous
//
#include <hip/hip_runtime.h>
#include <cmath>

namespace {

typedef __attribute__((ext_vector_type(8))) short short8;
typedef __attribute__((ext_vector_type(4))) float f32x4;
typedef __attribute__((ext_vector_type(4))) unsigned u32x4;

constexpr float kScale = 0.08838834764831845f;     // 128^-0.5
constexpr float kScaleL2 = 0.12751744900764504f;   // kScale * log2(e)

__device__ __forceinline__ int voxel_row(int p, int pix) {
  int pd = p >> 6, ph = (p >> 3) & 7, pw = p & 7;
  int iz = pix >> 4, iy = (pix >> 2) & 3, ix = pix & 3;
  return (((pd * 4 + iz) * 32 + (ph * 4 + iy)) * 32 + (pw * 4 + ix));
}

__device__ __forceinline__ float dot4(float4 a, float4 b) {
  return a.x * b.x + a.y * b.y + a.z * b.z + a.w * b.w;
}

__device__ __forceinline__ short bf16c(float f) {
  unsigned u = __builtin_bit_cast(unsigned, f);
  u += 0x7fffu + ((u >> 16) & 1u);
  return (short)(u >> 16);
}

__device__ __forceinline__ unsigned bfpack(float lo, float hi) {
  return (unsigned)(unsigned short)bf16c(lo) |
         ((unsigned)(unsigned short)bf16c(hi) << 16);
}

// ---- pack weights into per-lane MFMA B-fragments ----
__global__ __launch_bounds__(64) void k_pack2(
    const float* __restrict__ wqkv, const float* __restrict__ wo,
    short* __restrict__ dstq, short* __restrict__ dsto) {
  const int lane = threadIdx.x;
  const float* w;
  short* dst;
  int fid, N;
  if (blockIdx.x < 96) {
    w = wqkv; dst = dstq; fid = blockIdx.x; N = 384;
  } else {
    w = wo; dst = dsto; fid = blockIdx.x - 96; N = 128;
  }
  const int ntile = fid >> 2, ks = fid & 3;
  const int k0 = ks * 32 + (lane >> 4) * 8, col = ntile * 16 + (lane & 15);
  short8 o;
#pragma unroll
  for (int i = 0; i < 8; ++i) o[i] = bf16c(w[(size_t)(k0 + i) * N + col]);
  *(short8*)(dst + ((size_t)fid * 64 + lane) * 8) = o;
}

// ---- QKV projection: 512 thr / 8 waves x 3 col-tiles ----
__global__ __launch_bounds__(512, 4) void k_qkv(
    const float* __restrict__ x, const short* __restrict__ wpk,
    const float* __restrict__ bias, const float* __restrict__ wfull,
    float* __restrict__ q, float* __restrict__ k, float* __restrict__ v,
    short* __restrict__ vt, short* __restrict__ kbh, short* __restrict__ qbh,
    float* __restrict__ qwin, float* __restrict__ kwin) {
  __shared__ short sX[64][136];
  __shared__ float xpart[8][16][8];
  __shared__ float xm[128];
  const int p = blockIdx.x, t = threadIdx.x;
  const int wave = t >> 6, lane = t & 63, l15 = lane & 15, lg = lane >> 4;

  float ps[8] = {0.f, 0.f, 0.f, 0.f, 0.f, 0.f, 0.f, 0.f};
#pragma unroll
  for (int r = 0; r < 2; ++r) {
    int unit = t + r * 512;
    int row = unit >> 4, u = unit & 15;
    const float* src = x + (size_t)voxel_row(p, row) * 128 + u * 8;
    float4 a = *(const float4*)src, b = *(const float4*)(src + 4);
    ps[0] += a.x; ps[1] += a.y; ps[2] += a.z; ps[3] += a.w;
    ps[4] += b.x; ps[5] += b.y; ps[6] += b.z; ps[7] += b.w;
    short8 o;
    o[0] = bf16c(a.x); o[1] = bf16c(a.y); o[2] = bf16c(a.z); o[3] = bf16c(a.w);
    o[4] = bf16c(b.x); o[5] = bf16c(b.y); o[6] = bf16c(b.z); o[7] = bf16c(b.w);
    *(short8*)(&sX[row][u * 8]) = o;
  }
#pragma unroll
  for (int i = 0; i < 8; ++i) {
    ps[i] += __shfl_xor(ps[i], 16);
    ps[i] += __shfl_xor(ps[i], 32);
  }
  if (lg == 0)
#pragma unroll
    for (int i = 0; i < 8; ++i) xpart[wave][l15][i] = ps[i];
  __syncthreads();
  if (t < 128) {
    float s = 0.f;
#pragma unroll
    for (int w8 = 0; w8 < 8; ++w8) s += xpart[w8][t >> 3][t & 7];
    xm[t] = s * (1.f / 64.f);
  }

  f32x4 acc[4][3];
#pragma unroll
  for (int mt = 0; mt < 4; ++mt)
#pragma unroll
    for (int nt = 0; nt < 3; ++nt) acc[mt][nt] = f32x4{0.f, 0.f, 0.f, 0.f};
#pragma unroll
  for (int ks = 0; ks < 4; ++ks) {
    short8 a[4];
#pragma unroll
    for (int mt = 0; mt < 4; ++mt)
      a[mt] = *(const short8*)(&sX[mt * 16 + l15][ks * 32 + lg * 8]);
#pragma unroll
    for (int nt = 0; nt < 3; ++nt) {
      int ntg = wave * 3 + nt;
      short8 b = *(const short8*)(wpk + ((size_t)(ntg * 4 + ks) * 64 + lane) * 8);
#pragma unroll
      for (int mt = 0; mt < 4; ++mt)
        acc[mt][nt] = __builtin_amdgcn_mfma_f32_16x16x32_bf16(a[mt], b, acc[mt][nt], 0, 0, 0);
    }
  }
#pragma unroll
  for (int nt = 0; nt < 3; ++nt) {
    int n = (wave * 3 + nt) * 16 + l15;
    float bv = bias[n];
    float* dst = n < 128 ? q : (n < 256 ? k : v);
    int col = n & 127;
#pragma unroll
    for (int mt = 0; mt < 4; ++mt) {
      float o0 = acc[mt][nt][0] + bv, o1 = acc[mt][nt][1] + bv;
      float o2 = acc[mt][nt][2] + bv, o3 = acc[mt][nt][3] + bv;
      int row0 = mt * 16 + lg * 4;
      dst[(size_t)(p * 64 + row0 + 0) * 128 + col] = o0;
      dst[(size_t)(p * 64 + row0 + 1) * 128 + col] = o1;
      dst[(size_t)(p * 64 + row0 + 2) * 128 + col] = o2;
      dst[(size_t)(p * 64 + row0 + 3) * 128 + col] = o3;
      if (n >= 256) {
        uint2 pk;
        pk.x = bfpack(o0, o1);
        pk.y = bfpack(o2, o3);
        *(uint2*)(vt + (size_t)p * 8192 + (size_t)(n - 256) * 64 + row0) = pk;
      } else if (n >= 128) {
        int hh = (n - 128) >> 4, d = (n - 128) & 15;
        short* kd = kbh + (((size_t)(p * 8 + hh)) * 64 + row0) * 16 + d;
        kd[0] = bf16c(o0);
        kd[16] = bf16c(o1);
        kd[32] = bf16c(o2);
        kd[48] = bf16c(o3);
      } else {  // Q bf16 head-major, pre-scaled into log2 domain
        int hh = n >> 4, d = n & 15;
        short* qd = qbh + (((size_t)(p * 8 + hh)) * 64 + row0) * 16 + d;
        qd[0] = bf16c(o0 * kScaleL2);
        qd[16] = bf16c(o1 * kScaleL2);
        qd[32] = bf16c(o2 * kScaleL2);
        qd[48] = bf16c(o3 * kScaleL2);
      }
    }
  }

  __syncthreads();
  if (t < 256) {
    float acc2 = bias[t];
    for (int kk = 0; kk < 128; ++kk)
      acc2 = fmaf(xm[kk], wfull[(size_t)kk * 384 + t], acc2);
    if (t < 128) qwin[p * 128 + t] = acc2;
    else kwin[p * 128 + (t - 128)] = acc2;
  }
}

// ---- FUSED routing + attention + out-projection (R20-exact, best) ----
// Register-resident top-4; raw v_exp_f32; defer-max (THR=11, log2 domain).
__global__ __launch_bounds__(512, 4) void k_attn(
    const short* __restrict__ qbh, const short* __restrict__ kbh,
    const short* __restrict__ vt, const float* __restrict__ qwin,
    const float* __restrict__ kwin, const short* __restrict__ wpk_o,
    const float* __restrict__ b_o, float* __restrict__ out) {
  __shared__ float lgits[512];
  __shared__ float qs[128];
  __shared__ int widx[4];
  __shared__ short sO[64][136];

  const int p = blockIdx.x, t = threadIdx.x;
  const int h = t >> 6, lane = t & 63;
  const int l15 = lane & 15, lg = lane >> 4;

  // Q B-frags issued early
  const short* qw = qbh + ((size_t)(p * 8 + h)) * 1024;
  short8 qf[4];
#pragma unroll
  for (int nt = 0; nt < 4; ++nt) {
    if (lg < 2)
      qf[nt] = *(const short8*)(qw + (nt * 16 + l15) * 16 + lg * 8);
    else
      qf[nt] = short8{0, 0, 0, 0, 0, 0, 0, 0};
  }

  // ---- routing: logits (all threads) ----
  if (t < 32) *(float4*)(&qs[t * 4]) = *(const float4*)(qwin + p * 128 + t * 4);
  __syncthreads();
  {
    const float* kr = kwin + (size_t)t * 128;
    float s = 0.f;
    for (int c = 0; c < 128; c += 4)
      s += dot4(*(const float4*)(qs + c), *(const float4*)(kr + c));
    lgits[t] = s;
  }
  __syncthreads();
  // top-4 by wave 0: values register-resident, winner cleared locally
  if (h == 0) {
    float vals[8];
#pragma unroll
    for (int i = 0; i < 8; ++i) vals[i] = lgits[lane * 8 + i];
    for (int sel = 0; sel < 4; ++sel) {
      float bv = -1e30f;
      int bi = 0;
#pragma unroll
      for (int i = 0; i < 8; ++i) {
        int idx = lane * 8 + i;
        if (vals[i] > bv) { bv = vals[i]; bi = idx; }
      }
#pragma unroll
      for (int off = 32; off > 0; off >>= 1) {
        float ov = __shfl_xor(bv, off);
        int oi = __shfl_xor(bi, off);
        if (ov > bv || (ov == bv && oi < bi)) { bv = ov; bi = oi; }
      }
      if (lane == 0) widx[sel] = bi;
      if ((bi >> 3) == lane) vals[bi & 7] = -1e30f;
    }
  }
  __syncthreads();

  const int src0 = ((lg & 1) << 5) | l15;
  const int src1 = src0 + 16;

  float m_r[4] = {-1e30f, -1e30f, -1e30f, -1e30f};
  float l_r[4] = {0.f, 0.f, 0.f, 0.f};
  f32x4 oacc[4];
#pragma unroll
  for (int i = 0; i < 4; ++i) oacc[i] = f32x4{0.f, 0.f, 0.f, 0.f};

  // ---- attention (log2-domain scores, raw v_exp_f32, defer-max) ----
#pragma unroll
  for (int c = 0; c < 4; ++c) {
    const int wsel = widx[c];
    const short* kw = kbh + ((size_t)(wsel * 8 + h)) * 1024;
    short8 af[4];
#pragma unroll
    for (int mt = 0; mt < 4; ++mt) {
      if (lg < 2)
        af[mt] = *(const short8*)(kw + (mt * 16 + l15) * 16 + lg * 8);
      else
        af[mt] = short8{0, 0, 0, 0, 0, 0, 0, 0};
    }
    const short* vw = vt + (size_t)wsel * 8192 + (size_t)(h * 16 + l15) * 64 + lg * 8;
    short8 av0 = *(const short8*)(vw);
    short8 av1 = *(const short8*)(vw + 32);

#pragma unroll
    for (int np = 0; np < 2; ++np) {
      f32x4 s[4][2];
#pragma unroll
      for (int mt = 0; mt < 4; ++mt)
#pragma unroll
        for (int j2 = 0; j2 < 2; ++j2)
          s[mt][j2] = __builtin_amdgcn_mfma_f32_16x16x32_bf16(
              af[mt], qf[np * 2 + j2], f32x4{0.f, 0.f, 0.f, 0.f}, 0, 0, 0);

#pragma unroll
      for (int j2 = 0; j2 < 2; ++j2) {
        const int nt = np * 2 + j2;
        float mx = -1e30f;
#pragma unroll
        for (int mt = 0; mt < 4; ++mt)
#pragma unroll
          for (int j = 0; j < 4; ++j) mx = fmaxf(mx, s[mt][j2][j]);
        mx = fmaxf(mx, __shfl_xor(mx, 16));
        mx = fmaxf(mx, __shfl_xor(mx, 32));
        // defer-max: rescale only when running max grows materially
        if (!__all(mx <= m_r[nt] + 11.0f)) {
          float mnew = fmaxf(m_r[nt], mx);
          float sc = __builtin_amdgcn_exp2f(m_r[nt] - mnew);
          m_r[nt] = mnew;
          l_r[nt] *= sc;
          oacc[nt][0] *= sc; oacc[nt][1] *= sc;
          oacc[nt][2] *= sc; oacc[nt][3] *= sc;
        }
        float ls = 0.f;
#pragma unroll
        for (int mt = 0; mt < 4; ++mt)
#pragma unroll
          for (int j = 0; j < 4; ++j) {
            float e = __builtin_amdgcn_exp2f(s[mt][j2][j] - m_r[nt]);
            s[mt][j2][j] = e;
            ls += e;
          }
        ls += __shfl_xor(ls, 16);
        ls += __shfl_xor(ls, 32);
        l_r[nt] += ls;

        unsigned P2[4][2];
#pragma unroll
        for (int mt = 0; mt < 4; ++mt) {
          P2[mt][0] = bfpack(s[mt][j2][0], s[mt][j2][1]);
          P2[mt][1] = bfpack(s[mt][j2][2], s[mt][j2][3]);
        }
#pragma unroll
        for (int kt = 0; kt < 2; ++kt) {
          unsigned lo0 = (unsigned)__shfl((int)P2[2 * kt + 0][0], src0);
          unsigned hi0 = (unsigned)__shfl((int)P2[2 * kt + 1][0], src0);
          unsigned lo1 = (unsigned)__shfl((int)P2[2 * kt + 0][1], src0);
          unsigned hi1 = (unsigned)__shfl((int)P2[2 * kt + 1][1], src0);
          unsigned lo2 = (unsigned)__shfl((int)P2[2 * kt + 0][0], src1);
          unsigned hi2 = (unsigned)__shfl((int)P2[2 * kt + 1][0], src1);
          unsigned lo3 = (unsigned)__shfl((int)P2[2 * kt + 0][1], src1);
          unsigned hi3 = (unsigned)__shfl((int)P2[2 * kt + 1][1], src1);
          u32x4 bw;
          bw[0] = (lg < 2) ? lo0 : hi0;
          bw[1] = (lg < 2) ? lo1 : hi1;
          bw[2] = (lg < 2) ? lo2 : hi2;
          bw[3] = (lg < 2) ? lo3 : hi3;
          short8 bfr = __builtin_bit_cast(short8, bw);
          oacc[nt] = __builtin_amdgcn_mfma_f32_16x16x32_bf16(
              kt == 0 ? av0 : av1, bfr, oacc[nt], 0, 0, 0);
        }
      }
    }
  }

  // ---- O -> LDS (bf16), per-wave out-projection col tile ----
#pragma unroll
  for (int nt = 0; nt < 4; ++nt) {
    float inv = 1.f / l_r[nt];
    uint2 pk;
    pk.x = bfpack(oacc[nt][0] * inv, oacc[nt][1] * inv);
    pk.y = bfpack(oacc[nt][2] * inv, oacc[nt][3] * inv);
    *(uint2*)(&sO[nt * 16 + l15][h * 16 + lg * 4]) = pk;
  }
  __syncthreads();

  f32x4 pacc[4];
#pragma unroll
  for (int mt = 0; mt < 4; ++mt) pacc[mt] = f32x4{0.f, 0.f, 0.f, 0.f};
#pragma unroll
  for (int ks = 0; ks < 4; ++ks) {
    short8 a[4];
#pragma unroll
    for (int mt = 0; mt < 4; ++mt)
      a[mt] = *(const short8*)(&sO[mt * 16 + l15][ks * 32 + lg * 8]);
    short8 b = *(const short8*)(wpk_o + ((size_t)(h * 4 + ks) * 64 + lane) * 8);
#pragma unroll
    for (int mt = 0; mt < 4; ++mt)
      pacc[mt] = __builtin_amdgcn_mfma_f32_16x16x32_bf16(a[mt], b, pacc[mt], 0, 0, 0);
  }
  {
    int n = h * 16 + l15;
    float bv = b_o[n];
#pragma unroll
    for (int mt = 0; mt < 4; ++mt)
#pragma unroll
      for (int j = 0; j < 4; ++j)
        out[(size_t)voxel_row(p, mt * 16 + lg * 4 + j) * 128 + n] = pacc[mt][j] + bv;
  }
}

}  // namespace

extern "C" void kernel_launch(void* const* d_in, const int* in_sizes, int n_in,
                              void* d_out, int out_size, void* d_ws, size_t ws_size,
                              hipStream_t stream) {
  (void)in_sizes; (void)n_in; (void)out_size; (void)ws_size;
  const float* x = (const float*)d_in[0];
  const float* w_qkv = (const float*)d_in[1];
  const float* b_qkv = (const float*)d_in[2];
  const float* w_o = (const float*)d_in[3];
  const float* b_o = (const float*)d_in[4];

  float* out = (float*)d_out;
  float* q = out + 4194304;
  float* k = q + 4194304;
  float* v = k + 4194304;

  float* qwin = (float*)d_ws;                 // 512*128 f32
  float* kwin = qwin + 65536;                 // 512*128 f32
  short* wpk_qkv = (short*)(kwin + 65536);    // 96 KB
  short* wpk_o = wpk_qkv + 49152;             // 32 KB
  short* vt = wpk_o + 16384;                  // 8 MB
  short* kbh = vt + 4194304;                  // 8 MB
  short* qbh = kbh + 4194304;                 // 8 MB

  k_pack2<<<128, 64, 0, stream>>>(w_qkv, w_o, wpk_qkv, wpk_o);
  k_qkv<<<512, 512, 0, stream>>>(x, wpk_qkv, b_qkv, w_qkv, q, k, v, vt, kbh, qbh, qwin, kwin);
  k_attn<<<512, 512, 0, stream>>>(qbh, kbh, vt, qwin, kwin, wpk_o, b_o, out);
}